// Round 9
// baseline (187.170 us; speedup 1.0000x reference)
//
#include <hip/hip_runtime.h>
#include <math.h>

#define BB 256
#define LL 3
#define CC 8
#define VV 20
#define SS 32
#define DD 64
#define NG (BB * LL * CC)   // 6144 groups per segment
#define NWAVES 4096         // persistent waves (2048 blocks x 2)

typedef float v4f __attribute__((ext_vector_type(4)));

__device__ __forceinline__ float sigmoidf_(float x) { return 1.0f / (1.0f + __expf(-x)); }
__device__ __forceinline__ float dot4v_(v4f a, v4f b) {
    return a[0] * b[0] + a[1] * b[1] + a[2] * b[2] + a[3] * b[3];
}

// ---------------- K1: fused prologue (per-b block, 256 threads) ----------------
__global__ __launch_bounds__(256) void prologue(
    const float* __restrict__ E, const int* __restrict__ ucv, const int* __restrict__ ucl,
    const int* __restrict__ items, const int* __restrict__ icl, const int* __restrict__ negs,
    const int* __restrict__ ncl, const float* __restrict__ W, const float* __restrict__ W_ht,
    const float* __restrict__ Wc, const float* __restrict__ Wv, float* __restrict__ wcce_u,
    float* __restrict__ whv_u, float* __restrict__ wcce_i, float* __restrict__ wcce_n,
    float* __restrict__ ie_i, float* __restrict__ ie_n) {
    int b = blockIdx.x, tid = threadIdx.x;
    int d = tid & 63, q = tid >> 6;  // q in 0..3
    __shared__ float vcs[CC][DD];
    __shared__ float part[4][DD];
    __shared__ float part2[4][DD];
    __shared__ float cce_u_s[DD], vce_u_s[DD], cce_i_s[DD], cce_n_s[DD], vmean_s[DD];
    __shared__ float ie_s[2][DD];

    float p1 = 0.f;
    for (int cc = 0; cc < 2; ++cc) {
        int c = q + cc * 4;
        const int* iv = ucv + (b * CC + c) * VV;
        float a = 0.f;
#pragma unroll
        for (int v = 0; v < VV; ++v) a += E[(long)iv[v] * DD + d];
        vcs[c][d] = a;
        p1 += E[(long)ucl[b * CC + c] * DD + d];
    }
    part[q][d] = p1;
    __syncthreads();
    {
        float sacc = 0.f;
        for (int cc = 0; cc < 2; ++cc) {
            int c = q + cc * 4;
            float m = 0.f;
#pragma unroll 8
            for (int k = 0; k < DD; ++k) m += vcs[c][k] * Wc[k * DD + d];
            sacc += sigmoidf_(m);
        }
        part2[q][d] = sacc;
    }
    __syncthreads();
    if (q == 0) {
        float s = 0.f;
#pragma unroll
        for (int i = 0; i < 4; ++i) s += part[i][d] + part2[i][d];
        cce_u_s[d] = s * (1.f / CC);
        float vm = 0.f;
#pragma unroll
        for (int c = 0; c < CC; ++c) vm += vcs[c][d];
        vmean_s[d] = vm * (1.f / CC);
    }
    __syncthreads();
    {
        float m = 0.f;
        for (int k = q * 16; k < q * 16 + 16; ++k) m += vmean_s[k] * Wv[k * DD + d];
        part[q][d] = m;
    }
    {
        const int* cl = (q < 2) ? icl : ncl;
        int c0 = (q & 1) ? 5 : 1, c1 = (q & 1) ? 8 : 5;
        float m = 0.f;
        for (int c = c0; c < c1; ++c) m += E[(long)cl[b * CC + c] * DD + d];
        part2[q][d] = m;
        if (q == 1) ie_s[0][d] = E[(long)items[b] * DD + d];
        if (q == 3) ie_s[1][d] = E[(long)negs[b] * DD + d];
    }
    __syncthreads();
    if (q == 0) {
        vce_u_s[d] = sigmoidf_(part[0][d] + part[1][d] + part[2][d] + part[3][d]);
        float ie = ie_s[0][d];
        cce_i_s[d] = ie * (1.f + (part2[0][d] + part2[1][d]) * (1.f / 7.f));
        ie_i[b * DD + d] = ie;
    } else if (q == 1) {
        float ie = ie_s[1][d];
        cce_n_s[d] = ie * (1.f + (part2[2][d] + part2[3][d]) * (1.f / 7.f));
        ie_n[b * DD + d] = ie;
    }
    __syncthreads();
    {
        int k = tid & 127, sel = tid >> 7;
        const float* wr = (sel ? W_ht : W) + k * DD;
        const float* wr2 = W + k * DD;
        const float* v1 = sel ? vce_u_s : cce_u_s;
        const float* v2 = sel ? cce_n_s : cce_i_s;
        float a = 0.f, c2 = 0.f;
#pragma unroll 8
        for (int kk = 0; kk < DD; ++kk) {
            a += wr[kk] * v1[kk];
            c2 += wr2[kk] * v2[kk];
        }
        if (sel == 0) {
            wcce_u[b * 128 + k] = a;
            wcce_i[b * 128 + k] = c2;
        } else {
            whv_u[b * 128 + k] = a;
            wcce_n[b * 128 + k] = c2;
        }
    }
}

// ---------------- K2: layer_emb; persistent waves, grid-stride over groups -------------
// 128-thr blocks + launch_bounds(128,8): VGPR<=64 -> 8 waves/SIMD -> 32 waves/CU.
// TLP (not per-wave MLP) hides gather latency; R8 proved throughput tracks wave count.
__global__ __launch_bounds__(128, 8) void layer_all(
    const float* __restrict__ E, const float* __restrict__ R, const int* __restrict__ uts,
    const int* __restrict__ its, const int* __restrict__ nts, const float* __restrict__ wcce_u,
    const float* __restrict__ whv_u, const float* __restrict__ wcce_i,
    const float* __restrict__ wcce_n, float* __restrict__ o_all) {
    int tid = threadIdx.x;
    int lane = tid & 63;
    int f = lane & 15, grp = lane >> 4;  // 16 f-lanes x 4 row-groups
    int wave0 = blockIdx.x * 2 + (tid >> 6);

    for (int gg = wave0; gg < 3 * NG; gg += NWAVES) {
        int seg = gg / NG;
        int g = gg - seg * NG;
        int b = g / (LL * CC);
        const int* ts = (seg == 0) ? uts : (seg == 1) ? its : nts;
        const float* wcp = (seg == 0) ? wcce_u : (seg == 1) ? wcce_i : wcce_n;
        const bool has_p2 = (seg == 0);
        const int* tg = ts + (long)g * 3 * SS;

        // coalesced index loads + broadcast
        int idx_a = tg[lane];
        int idx_b = tg[64 + (lane & 31)];
        int hix[8], rix[8], tix[8];
#pragma unroll
        for (int p = 0; p < 8; ++p) {
            int row = p * 4 + grp;
            hix[p] = __shfl(idx_a, row, 64);
            rix[p] = __shfl(idx_a, 32 + row, 64);
            tix[p] = __shfl(idx_b, row, 64);
        }
        const v4f* wc4 = (const v4f*)(wcp + b * 128);
        v4f wc_h = wc4[f], wc_r = wc4[f + 16];
        v4f wh_h = {0.f, 0.f, 0.f, 0.f}, wh_t = wh_h;
        if (has_p2) {
            const v4f* wh4 = (const v4f*)(whv_u + b * 128);
            wh_h = wh4[f];
            wh_t = wh4[f + 16];
        }
        v4f hv[8], rv[8], t4[8];
#pragma unroll
        for (int p = 0; p < 8; ++p) hv[p] = *(const v4f*)(E + (long)hix[p] * DD + f * 4);
#pragma unroll
        for (int p = 0; p < 8; ++p) rv[p] = *(const v4f*)(R + (long)rix[p] * DD + f * 4);
#pragma unroll
        for (int p = 0; p < 8; ++p) t4[p] = *(const v4f*)(E + (long)tix[p] * DD + f * 4);

        float s1[8], s2[8];
#pragma unroll
        for (int p = 0; p < 8; ++p) {
            float a1 = dot4v_(hv[p], wc_h) + dot4v_(rv[p], wc_r);
#pragma unroll
            for (int m = 1; m < 16; m <<= 1) a1 += __shfl_xor(a1, m, 64);
            s1[p] = a1;
        }
        if (has_p2) {
#pragma unroll
            for (int p = 0; p < 8; ++p) {
                float a2 = dot4v_(hv[p], wh_h) + dot4v_(t4[p], wh_t);
#pragma unroll
                for (int m = 1; m < 16; m <<= 1) a2 += __shfl_xor(a2, m, 64);
                s2[p] = a2;
            }
        }
        // softmax over the 32 rows (8 per lane-column x 4 grps)
        float mx = -1e30f;
#pragma unroll
        for (int p = 0; p < 8; ++p) {
            s1[p] = sigmoidf_(s1[p]);
            mx = fmaxf(mx, s1[p]);
        }
        mx = fmaxf(mx, __shfl_xor(mx, 16, 64));
        mx = fmaxf(mx, __shfl_xor(mx, 32, 64));
        float se = 0.f;
#pragma unroll
        for (int p = 0; p < 8; ++p) {
            s1[p] = __expf(s1[p] - mx);
            se += s1[p];
        }
        se += __shfl_xor(se, 16, 64);
        se += __shfl_xor(se, 32, 64);
        float inv = 1.f / se;
        float4 oacc = make_float4(0.f, 0.f, 0.f, 0.f);
#pragma unroll
        for (int p = 0; p < 8; ++p) {
            float wgt = s1[p] * inv;
            if (has_p2) wgt *= sigmoidf_(s2[p]);
            oacc.x += wgt * t4[p][0];
            oacc.y += wgt * t4[p][1];
            oacc.z += wgt * t4[p][2];
            oacc.w += wgt * t4[p][3];
        }
#pragma unroll
        for (int m = 16; m <= 32; m <<= 1) {
            oacc.x += __shfl_xor(oacc.x, m, 64);
            oacc.y += __shfl_xor(oacc.y, m, 64);
            oacc.z += __shfl_xor(oacc.z, m, 64);
            oacc.w += __shfl_xor(oacc.w, m, 64);
        }
        float qq = oacc.x * oacc.x + oacc.y * oacc.y + oacc.z * oacc.z + oacc.w * oacc.w;
#pragma unroll
        for (int m = 1; m < 16; m <<= 1) qq += __shfl_xor(qq, m, 64);
        float innorm = 1.f / fmaxf(sqrtf(qq), 1e-12f);
        if (grp == 0) {
            oacc.x *= innorm;
            oacc.y *= innorm;
            oacc.z *= innorm;
            oacc.w *= innorm;
            *(float4*)(o_all + (long)gg * DD + f * 4) = oacc;
        }
    }
}

// ---------------- K3: fused postlude (per-b block, 3 waves; o already normalized) -------
__global__ __launch_bounds__(192) void postlude(const float* __restrict__ o_all,
                                                const float* __restrict__ ie_i,
                                                const float* __restrict__ ie_n,
                                                float* __restrict__ out) {
    int b = blockIdx.x, tid = threadIdx.x;
    int w = tid / 64, d = tid & 63;
    __shared__ float u_s[DD], ci_s[DD], cn_s[DD];
    if (w == 0) {
        const float* o_u = o_all + (long)b * LL * CC * DD;
        float acc = 0.f;
#pragma unroll
        for (int lc = 0; lc < LL * CC; ++lc) acc += o_u[lc * DD + d];
        u_s[d] = acc * (1.f / CC);
    } else {
        const float* o_c = o_all + ((long)w * NG + (long)b * LL * CC) * DD;
        const float* ie_buf = (w == 1) ? ie_i : ie_n;
        float cs[CC];
#pragma unroll
        for (int c = 0; c < CC; ++c) {
            float a = 0.f;
#pragma unroll
            for (int l = 0; l < LL; ++l) a += o_c[(l * CC + c) * DD + d];
            cs[c] = a;
        }
        float p[CC - 1];
        float mx = -1e30f;
        for (int c = 0; c < CC - 1; ++c) {
            float dd2 = cs[0] * cs[c + 1];
#pragma unroll
            for (int m = 32; m > 0; m >>= 1) dd2 += __shfl_xor(dd2, m, 64);
            p[c] = sigmoidf_(dd2);
            mx = fmaxf(mx, p[c]);
        }
        float se = 0.f;
        for (int c = 0; c < CC - 1; ++c) {
            p[c] = __expf(p[c] - mx);
            se += p[c];
        }
        float mcf = 0.f;
        for (int c = 0; c < CC - 1; ++c) mcf += (p[c] / se) * cs[c + 1];
        float ie = ie_buf[b * DD + d];
        float ad = ie * mcf;
#pragma unroll
        for (int m = 32; m > 0; m >>= 1) ad += __shfl_xor(ad, m, 64);
        float alpha = sigmoidf_(ad);
        float res = alpha / (1.f + alpha) * mcf + cs[0] + ie;
        if (w == 1)
            ci_s[d] = res;
        else
            cn_s[d] = res;
    }
    __syncthreads();
    if (w == 0) {
        float uv = u_s[d];
        float s1 = uv * ci_s[d];
        float s2 = uv * cn_s[d];
#pragma unroll
        for (int m = 32; m > 0; m >>= 1) {
            s1 += __shfl_xor(s1, m, 64);
            s2 += __shfl_xor(s2, m, 64);
        }
        if (d == 0) {
            out[b] = s1;
            out[BB + b] = s2;
        }
    }
}

extern "C" void kernel_launch(void* const* d_in, const int* in_sizes, int n_in,
                              void* d_out, int out_size, void* d_ws, size_t ws_size,
                              hipStream_t stream) {
    const int* ucv = (const int*)d_in[0];
    const int* items = (const int*)d_in[1];
    const int* negs = (const int*)d_in[2];
    const int* uts = (const int*)d_in[3];
    const int* its = (const int*)d_in[4];
    const int* nts = (const int*)d_in[5];
    const int* ucl = (const int*)d_in[6];
    const int* icl = (const int*)d_in[7];
    const int* ncl = (const int*)d_in[8];
    const float* E = (const float*)d_in[9];
    const float* R = (const float*)d_in[10];
    const float* W = (const float*)d_in[11];
    const float* W_ht = (const float*)d_in[12];
    const float* Wc = (const float*)d_in[13];
    const float* Wv = (const float*)d_in[14];

    float* ws = (float*)d_ws;
    float* wcce_u = ws;                 // B*128
    float* whv_u = wcce_u + BB * 128;   // B*128
    float* wcce_i = whv_u + BB * 128;   // B*128
    float* wcce_n = wcce_i + BB * 128;  // B*128
    float* ie_i = wcce_n + BB * 128;    // B*64
    float* ie_n = ie_i + BB * DD;       // B*64
    float* o_all = ie_n + BB * DD;      // 3*NG*64

    prologue<<<BB, 256, 0, stream>>>(E, ucv, ucl, items, icl, negs, ncl, W, W_ht, Wc, Wv,
                                     wcce_u, whv_u, wcce_i, wcce_n, ie_i, ie_n);
    layer_all<<<NWAVES / 2, 128, 0, stream>>>(E, R, uts, its, nts, wcce_u, whv_u, wcce_i,
                                              wcce_n, o_all);
    postlude<<<BB, 192, 0, stream>>>(o_all, ie_i, ie_n, (float*)d_out);
}

// Round 10
// 64.821 us; speedup vs baseline: 2.8875x; 2.8875x over previous
//
#include <hip/hip_runtime.h>
#include <math.h>

#define BB 256
#define LL 3
#define CC 8
#define VV 20
#define SS 32
#define DD 64
#define NG (BB * LL * CC)  // 6144 groups per segment

typedef float v4f __attribute__((ext_vector_type(4)));

__device__ __forceinline__ float sigmoidf_(float x) { return 1.0f / (1.0f + __expf(-x)); }
__device__ __forceinline__ float dot4v_(v4f a, v4f b) {
    return a[0] * b[0] + a[1] * b[1] + a[2] * b[2] + a[3] * b[3];
}

// ---------------- K1: fused prologue (per-b block, 256 threads) ----------------
__global__ __launch_bounds__(256) void prologue(
    const float* __restrict__ E, const int* __restrict__ ucv, const int* __restrict__ ucl,
    const int* __restrict__ items, const int* __restrict__ icl, const int* __restrict__ negs,
    const int* __restrict__ ncl, const float* __restrict__ W, const float* __restrict__ W_ht,
    const float* __restrict__ Wc, const float* __restrict__ Wv, float* __restrict__ wcce_u,
    float* __restrict__ whv_u, float* __restrict__ wcce_i, float* __restrict__ wcce_n,
    float* __restrict__ ie_i, float* __restrict__ ie_n) {
    int b = blockIdx.x, tid = threadIdx.x;
    int d = tid & 63, q = tid >> 6;  // q in 0..3
    __shared__ float vcs[CC][DD];
    __shared__ float part[4][DD];
    __shared__ float part2[4][DD];
    __shared__ float cce_u_s[DD], vce_u_s[DD], cce_i_s[DD], cce_n_s[DD], vmean_s[DD];
    __shared__ float ie_s[2][DD];

    float p1 = 0.f;
    for (int cc = 0; cc < 2; ++cc) {
        int c = q + cc * 4;
        const int* iv = ucv + (b * CC + c) * VV;
        float a = 0.f;
#pragma unroll
        for (int v = 0; v < VV; ++v) a += E[(long)iv[v] * DD + d];
        vcs[c][d] = a;
        p1 += E[(long)ucl[b * CC + c] * DD + d];
    }
    part[q][d] = p1;
    __syncthreads();
    {
        float sacc = 0.f;
        for (int cc = 0; cc < 2; ++cc) {
            int c = q + cc * 4;
            float m = 0.f;
#pragma unroll 8
            for (int k = 0; k < DD; ++k) m += vcs[c][k] * Wc[k * DD + d];
            sacc += sigmoidf_(m);
        }
        part2[q][d] = sacc;
    }
    __syncthreads();
    if (q == 0) {
        float s = 0.f;
#pragma unroll
        for (int i = 0; i < 4; ++i) s += part[i][d] + part2[i][d];
        cce_u_s[d] = s * (1.f / CC);
        float vm = 0.f;
#pragma unroll
        for (int c = 0; c < CC; ++c) vm += vcs[c][d];
        vmean_s[d] = vm * (1.f / CC);
    }
    __syncthreads();
    {
        float m = 0.f;
        for (int k = q * 16; k < q * 16 + 16; ++k) m += vmean_s[k] * Wv[k * DD + d];
        part[q][d] = m;
    }
    {
        const int* cl = (q < 2) ? icl : ncl;
        int c0 = (q & 1) ? 5 : 1, c1 = (q & 1) ? 8 : 5;
        float m = 0.f;
        for (int c = c0; c < c1; ++c) m += E[(long)cl[b * CC + c] * DD + d];
        part2[q][d] = m;
        if (q == 1) ie_s[0][d] = E[(long)items[b] * DD + d];
        if (q == 3) ie_s[1][d] = E[(long)negs[b] * DD + d];
    }
    __syncthreads();
    if (q == 0) {
        vce_u_s[d] = sigmoidf_(part[0][d] + part[1][d] + part[2][d] + part[3][d]);
        float ie = ie_s[0][d];
        cce_i_s[d] = ie * (1.f + (part2[0][d] + part2[1][d]) * (1.f / 7.f));
        ie_i[b * DD + d] = ie;
    } else if (q == 1) {
        float ie = ie_s[1][d];
        cce_n_s[d] = ie * (1.f + (part2[2][d] + part2[3][d]) * (1.f / 7.f));
        ie_n[b * DD + d] = ie;
    }
    __syncthreads();
    {
        int k = tid & 127, sel = tid >> 7;
        const float* wr = (sel ? W_ht : W) + k * DD;
        const float* wr2 = W + k * DD;
        const float* v1 = sel ? vce_u_s : cce_u_s;
        const float* v2 = sel ? cce_n_s : cce_i_s;
        float a = 0.f, c2 = 0.f;
#pragma unroll 8
        for (int kk = 0; kk < DD; ++kk) {
            a += wr[kk] * v1[kk];
            c2 += wr2[kk] * v2[kk];
        }
        if (sel == 0) {
            wcce_u[b * 128 + k] = a;
            wcce_i[b * 128 + k] = c2;
        } else {
            whv_u[b * 128 + k] = a;
            wcce_n[b * 128 + k] = c2;
        }
    }
}

// ---------------- K2: layer_emb; consumer-side pin forces a true 24-deep load batch ----
// The empty asm with "+v" on all 24 gather results is the FIRST consumer: loads can't
// sink below it, compute can't hoist above it, and RA must keep all 24 values live
// simultaneously (>=96 VGPR). One vmcnt(0) drain pays ~1 L3 latency for all 24 loads.
__global__ __launch_bounds__(256, 2) void layer_all(
    const float* __restrict__ E, const float* __restrict__ R, const int* __restrict__ uts,
    const int* __restrict__ its, const int* __restrict__ nts, const float* __restrict__ wcce_u,
    const float* __restrict__ whv_u, const float* __restrict__ wcce_i,
    const float* __restrict__ wcce_n, float* __restrict__ o_all) {
    int tid = threadIdx.x;
    int w = tid >> 6, lane = tid & 63;
    int f = lane & 15, grp = lane >> 4;  // 16 f-lanes x 4 row-groups
    int gg = blockIdx.x * 4 + w;
    int seg = gg / NG;
    int g = gg - seg * NG;
    int b = g / (LL * CC);
    const int* ts = (seg == 0) ? uts : (seg == 1) ? its : nts;
    const float* wcp = (seg == 0) ? wcce_u : (seg == 1) ? wcce_i : wcce_n;
    const bool has_p2 = (seg == 0);
    const int* tg = ts + (long)g * 3 * SS;

    // coalesced index loads + broadcast
    int idx_a = tg[lane];
    int idx_b = tg[64 + (lane & 31)];
    int hix[8], rix[8], tix[8];
#pragma unroll
    for (int p = 0; p < 8; ++p) {
        int row = p * 4 + grp;
        hix[p] = __shfl(idx_a, row, 64);
        rix[p] = __shfl(idx_a, 32 + row, 64);
        tix[p] = __shfl(idx_b, row, 64);
    }
    const v4f* wc4 = (const v4f*)(wcp + b * 128);
    v4f wc_h = wc4[f], wc_r = wc4[f + 16];
    v4f wh_h = {0.f, 0.f, 0.f, 0.f}, wh_t = wh_h;
    if (has_p2) {
        const v4f* wh4 = (const v4f*)(whv_u + b * 128);
        wh_h = wh4[f];
        wh_t = wh4[f + 16];
    }
    // issue all 24 row gathers
    v4f hv[8], rv[8], t4[8];
#pragma unroll
    for (int p = 0; p < 8; ++p) hv[p] = *(const v4f*)(E + (long)hix[p] * DD + f * 4);
#pragma unroll
    for (int p = 0; p < 8; ++p) rv[p] = *(const v4f*)(R + (long)rix[p] * DD + f * 4);
#pragma unroll
    for (int p = 0; p < 8; ++p) t4[p] = *(const v4f*)(E + (long)tix[p] * DD + f * 4);
    // consumer-side pin: all 24 results simultaneously live here.
    asm volatile(""
                 : "+v"(hv[0]), "+v"(hv[1]), "+v"(hv[2]), "+v"(hv[3]), "+v"(hv[4]),
                   "+v"(hv[5]), "+v"(hv[6]), "+v"(hv[7]), "+v"(rv[0]), "+v"(rv[1]),
                   "+v"(rv[2]), "+v"(rv[3]), "+v"(rv[4]), "+v"(rv[5]), "+v"(rv[6]),
                   "+v"(rv[7]), "+v"(t4[0]), "+v"(t4[1]), "+v"(t4[2]), "+v"(t4[3]),
                   "+v"(t4[4]), "+v"(t4[5]), "+v"(t4[6]), "+v"(t4[7]));

    float s1[8], s2[8];
#pragma unroll
    for (int p = 0; p < 8; ++p) {
        float a1 = dot4v_(hv[p], wc_h) + dot4v_(rv[p], wc_r);
#pragma unroll
        for (int m = 1; m < 16; m <<= 1) a1 += __shfl_xor(a1, m, 64);
        s1[p] = a1;
    }
    if (has_p2) {
#pragma unroll
        for (int p = 0; p < 8; ++p) {
            float a2 = dot4v_(hv[p], wh_h) + dot4v_(t4[p], wh_t);
#pragma unroll
            for (int m = 1; m < 16; m <<= 1) a2 += __shfl_xor(a2, m, 64);
            s2[p] = a2;
        }
    }
    // softmax over the 32 rows (8 per lane-column x 4 grps)
    float mx = -1e30f;
#pragma unroll
    for (int p = 0; p < 8; ++p) {
        s1[p] = sigmoidf_(s1[p]);
        mx = fmaxf(mx, s1[p]);
    }
    mx = fmaxf(mx, __shfl_xor(mx, 16, 64));
    mx = fmaxf(mx, __shfl_xor(mx, 32, 64));
    float se = 0.f;
#pragma unroll
    for (int p = 0; p < 8; ++p) {
        s1[p] = __expf(s1[p] - mx);
        se += s1[p];
    }
    se += __shfl_xor(se, 16, 64);
    se += __shfl_xor(se, 32, 64);
    float inv = 1.f / se;
    float4 oacc = make_float4(0.f, 0.f, 0.f, 0.f);
#pragma unroll
    for (int p = 0; p < 8; ++p) {
        float wgt = s1[p] * inv;
        if (has_p2) wgt *= sigmoidf_(s2[p]);
        oacc.x += wgt * t4[p][0];
        oacc.y += wgt * t4[p][1];
        oacc.z += wgt * t4[p][2];
        oacc.w += wgt * t4[p][3];
    }
#pragma unroll
    for (int m = 16; m <= 32; m <<= 1) {
        oacc.x += __shfl_xor(oacc.x, m, 64);
        oacc.y += __shfl_xor(oacc.y, m, 64);
        oacc.z += __shfl_xor(oacc.z, m, 64);
        oacc.w += __shfl_xor(oacc.w, m, 64);
    }
    float qq = oacc.x * oacc.x + oacc.y * oacc.y + oacc.z * oacc.z + oacc.w * oacc.w;
#pragma unroll
    for (int m = 1; m < 16; m <<= 1) qq += __shfl_xor(qq, m, 64);
    float innorm = 1.f / fmaxf(sqrtf(qq), 1e-12f);
    if (grp == 0) {
        oacc.x *= innorm;
        oacc.y *= innorm;
        oacc.z *= innorm;
        oacc.w *= innorm;
        *(float4*)(o_all + (long)gg * DD + f * 4) = oacc;
    }
}

// ---------------- K3: fused postlude (per-b block, 3 waves; o already normalized) -------
__global__ __launch_bounds__(192) void postlude(const float* __restrict__ o_all,
                                                const float* __restrict__ ie_i,
                                                const float* __restrict__ ie_n,
                                                float* __restrict__ out) {
    int b = blockIdx.x, tid = threadIdx.x;
    int w = tid / 64, d = tid & 63;
    __shared__ float u_s[DD], ci_s[DD], cn_s[DD];
    if (w == 0) {
        const float* o_u = o_all + (long)b * LL * CC * DD;
        float acc = 0.f;
#pragma unroll
        for (int lc = 0; lc < LL * CC; ++lc) acc += o_u[lc * DD + d];
        u_s[d] = acc * (1.f / CC);
    } else {
        const float* o_c = o_all + ((long)w * NG + (long)b * LL * CC) * DD;
        const float* ie_buf = (w == 1) ? ie_i : ie_n;
        float cs[CC];
#pragma unroll
        for (int c = 0; c < CC; ++c) {
            float a = 0.f;
#pragma unroll
            for (int l = 0; l < LL; ++l) a += o_c[(l * CC + c) * DD + d];
            cs[c] = a;
        }
        float p[CC - 1];
        float mx = -1e30f;
        for (int c = 0; c < CC - 1; ++c) {
            float dd2 = cs[0] * cs[c + 1];
#pragma unroll
            for (int m = 32; m > 0; m >>= 1) dd2 += __shfl_xor(dd2, m, 64);
            p[c] = sigmoidf_(dd2);
            mx = fmaxf(mx, p[c]);
        }
        float se = 0.f;
        for (int c = 0; c < CC - 1; ++c) {
            p[c] = __expf(p[c] - mx);
            se += p[c];
        }
        float mcf = 0.f;
        for (int c = 0; c < CC - 1; ++c) mcf += (p[c] / se) * cs[c + 1];
        float ie = ie_buf[b * DD + d];
        float ad = ie * mcf;
#pragma unroll
        for (int m = 32; m > 0; m >>= 1) ad += __shfl_xor(ad, m, 64);
        float alpha = sigmoidf_(ad);
        float res = alpha / (1.f + alpha) * mcf + cs[0] + ie;
        if (w == 1)
            ci_s[d] = res;
        else
            cn_s[d] = res;
    }
    __syncthreads();
    if (w == 0) {
        float uv = u_s[d];
        float s1 = uv * ci_s[d];
        float s2 = uv * cn_s[d];
#pragma unroll
        for (int m = 32; m > 0; m >>= 1) {
            s1 += __shfl_xor(s1, m, 64);
            s2 += __shfl_xor(s2, m, 64);
        }
        if (d == 0) {
            out[b] = s1;
            out[BB + b] = s2;
        }
    }
}

extern "C" void kernel_launch(void* const* d_in, const int* in_sizes, int n_in,
                              void* d_out, int out_size, void* d_ws, size_t ws_size,
                              hipStream_t stream) {
    const int* ucv = (const int*)d_in[0];
    const int* items = (const int*)d_in[1];
    const int* negs = (const int*)d_in[2];
    const int* uts = (const int*)d_in[3];
    const int* its = (const int*)d_in[4];
    const int* nts = (const int*)d_in[5];
    const int* ucl = (const int*)d_in[6];
    const int* icl = (const int*)d_in[7];
    const int* ncl = (const int*)d_in[8];
    const float* E = (const float*)d_in[9];
    const float* R = (const float*)d_in[10];
    const float* W = (const float*)d_in[11];
    const float* W_ht = (const float*)d_in[12];
    const float* Wc = (const float*)d_in[13];
    const float* Wv = (const float*)d_in[14];

    float* ws = (float*)d_ws;
    float* wcce_u = ws;                 // B*128
    float* whv_u = wcce_u + BB * 128;   // B*128
    float* wcce_i = whv_u + BB * 128;   // B*128
    float* wcce_n = wcce_i + BB * 128;  // B*128
    float* ie_i = wcce_n + BB * 128;    // B*64
    float* ie_n = ie_i + BB * DD;       // B*64
    float* o_all = ie_n + BB * DD;      // 3*NG*64

    prologue<<<BB, 256, 0, stream>>>(E, ucv, ucl, items, icl, negs, ncl, W, W_ht, Wc, Wv,
                                     wcce_u, whv_u, wcce_i, wcce_n, ie_i, ie_n);
    layer_all<<<(3 * NG) / 4, 256, 0, stream>>>(E, R, uts, its, nts, wcce_u, whv_u, wcce_i,
                                                wcce_n, o_all);
    postlude<<<BB, 192, 0, stream>>>(o_all, ie_i, ie_n, (float*)d_out);
}